// Round 10
// baseline (58.428 us; speedup 1.0000x reference)
//
#include <hip/hip_runtime.h>
#include <hip/hip_bf16.h>
#include <cstdint>

#define N_NODES 4096
#define FIN     128
#define FOUT    64
#define NHEAD   8
#define C_TOT   512   // NHEAD*FOUT
#define ECAP    192   // per-row edge capacity (= 3*64; mean deg ~82, sigma ~9)
#define LDK     136   // padded K-stride (bf16 elems)
#define GPB     8     // nodes (graph rows) per block in k_fused

typedef float fx4    __attribute__((ext_vector_type(4)));
typedef short bf16x8 __attribute__((ext_vector_type(8)));
typedef float f32x4  __attribute__((ext_vector_type(4)));

__device__ __forceinline__ float lrelu(float v){ return v > 0.f ? v : 0.2f*v; }

__device__ __forceinline__ ushort f2b(float f){
    uint u = __float_as_uint(f);
    return (ushort)((u + 0x7FFFu + ((u >> 16) & 1u)) >> 16);
}

// ---------------------------------------------------------------------------
// Kernel 1: MFMA bf16 GEMM (R6-proven, unchanged). grid (64, 9), 256 thr.
//   y = 0..7 : p-head GEMM + svec epilogue + bf16 head-minor store pb[n][c][h]
//   y = 8    : skip GEMM with inline head-averaged skip_w (f32 out, stride 64)
// ---------------------------------------------------------------------------
__global__ __launch_bounds__(256) void k_gemm(const float* __restrict__ x,
        const float* __restrict__ proj, const float* __restrict__ skip_w,
        const float* __restrict__ a_src, const float* __restrict__ a_tgt,
        __hip_bfloat16* __restrict__ pb, float* __restrict__ s_src_t,
        float* __restrict__ s_tgt_t, float* __restrict__ skipbar){
    __shared__ ushort xs[64*LDK];   // A tile
    __shared__ ushort bs[64*LDK];   // B^T tile
    int tid = threadIdx.x;
    int n0  = blockIdx.x * 64;
    int h   = blockIdx.y;

    #pragma unroll
    for (int k=0; k<8; k++){
        int q = tid + k*256;
        int r = q >> 5, f0 = (q & 31)*4;
        float4 v = *(const float4*)(x + (size_t)(n0+r)*FIN + f0);
        ushort4 u = make_ushort4(f2b(v.x), f2b(v.y), f2b(v.z), f2b(v.w));
        *(ushort4*)(xs + r*LDK + f0) = u;
    }
    if (h < 8){
        const float* B = proj + (size_t)h*FIN*FOUT;
        #pragma unroll
        for (int k=0; k<8; k++){
            int q = tid + k*256;
            int f = q >> 4, o0 = (q & 15)*4;
            float4 v = *(const float4*)(B + f*64 + o0);
            bs[(o0+0)*LDK + f] = f2b(v.x);
            bs[(o0+1)*LDK + f] = f2b(v.y);
            bs[(o0+2)*LDK + f] = f2b(v.z);
            bs[(o0+3)*LDK + f] = f2b(v.w);
        }
    } else {
        #pragma unroll
        for (int k=0; k<8; k++){
            int q = tid + k*256;
            int o = q >> 5, f0 = (q & 31)*4;
            float sx=0.f, sy=0.f, sz=0.f, sw=0.f;
            #pragma unroll
            for (int hh=0; hh<8; hh++){
                float4 v = *(const float4*)(skip_w + (size_t)(hh*64+o)*FIN + f0);
                sx += v.x; sy += v.y; sz += v.z; sw += v.w;
            }
            ushort4 u = make_ushort4(f2b(sx*0.125f), f2b(sy*0.125f),
                                     f2b(sz*0.125f), f2b(sw*0.125f));
            *(ushort4*)(bs + o*LDK + f0) = u;
        }
    }
    __syncthreads();

    int lane = tid & 63, w = tid >> 6;
    int r16 = lane & 15, kg = lane >> 4;
    f32x4 acc[4] = {{0.f,0.f,0.f,0.f},{0.f,0.f,0.f,0.f},
                    {0.f,0.f,0.f,0.f},{0.f,0.f,0.f,0.f}};
    const ushort* arow = xs + (w*16 + r16)*LDK + kg*8;
    #pragma unroll
    for (int ks=0; ks<4; ks++){
        bf16x8 a = *(const bf16x8*)(arow + ks*32);
        #pragma unroll
        for (int ct=0; ct<4; ct++){
            bf16x8 b = *(const bf16x8*)(bs + (ct*16 + r16)*LDK + ks*32 + kg*8);
            acc[ct] = __builtin_amdgcn_mfma_f32_16x16x32_bf16(a, b, acc[ct], 0, 0, 0);
        }
    }

    int rowbase = n0 + w*16 + kg*4;
    if (h < 8){
        float as[4], at[4];
        #pragma unroll
        for (int ct=0; ct<4; ct++){
            as[ct] = a_src[h*64 + ct*16 + r16];
            at[ct] = a_tgt[h*64 + ct*16 + r16];
        }
        ushort* pbu = (ushort*)pb;
        #pragma unroll
        for (int r=0; r<4; r++){
            float vs = 0.f, vt = 0.f;
            #pragma unroll
            for (int ct=0; ct<4; ct++){
                float v = acc[ct][r];
                vs = fmaf(v, as[ct], vs);
                vt = fmaf(v, at[ct], vt);
                pbu[(size_t)(rowbase+r)*C_TOT + (ct*16 + r16)*8 + h] = f2b(v);
            }
            #pragma unroll
            for (int off=1; off<16; off<<=1){
                vs += __shfl_xor(vs, off);
                vt += __shfl_xor(vt, off);
            }
            if (r16 == 0){
                s_src_t[(size_t)(rowbase+r)*8 + h] = vs;
                s_tgt_t[(size_t)(rowbase+r)*8 + h] = vt;
            }
        }
    } else {
        #pragma unroll
        for (int r=0; r<4; r++)
            #pragma unroll
            for (int ct=0; ct<4; ct++)
                skipbar[(size_t)(rowbase+r)*FOUT + ct*16 + r16] = acc[ct][r];
    }
}

// ---------------------------------------------------------------------------
// Kernel 2: producer/consumer fused GAT. 4 waves/block, GPB=8 nodes/block,
//   grid 512 (2 blocks/CU).
//   Wave 3 (producer): phases A+B for all 8 rows — streams topology (HBM),
//     builds compacted edge lists in LDS, release-flags each row.
//   Waves 0-2 (consumers): spin -> phases C+D (softmax + L2 gather-FMA).
//   Producer HBM traffic overlaps consumer L2 traffic on the same CU (TLP),
//   with no vmcnt FIFO coupling between the two streams.
// ---------------------------------------------------------------------------
__global__ __launch_bounds__(256) void k_fused(const float* __restrict__ topo,
        const __hip_bfloat16* __restrict__ pb, const float* __restrict__ s_src_t,
        const float* __restrict__ s_tgt_t, const float* __restrict__ skipbar,
        float* __restrict__ out){
    __shared__ ushort jlds[GPB*ECAP];         // 3 KB   edge cols per node
    __shared__ ushort wbf [3*ECAP*NHEAD];     // 9 KB   bf16 w strips (per consumer)
    __shared__ int    nelds[GPB];
    __shared__ int    flagv[GPB];

    int tid  = threadIdx.x;
    int lane = tid & 63, wv = tid >> 6;
    int n0   = blockIdx.x * GPB;

    if (tid < GPB) flagv[tid] = 0;
    __syncthreads();                          // the only block barrier

    if (wv == 3){
        // ================= PRODUCER: A + B for GPB rows =================
        for (int g=0; g<GPB; g++){
            int i = n0 + g;
            const fx4* tp = (const fx4*)(topo + (size_t)i*N_NODES);
            unsigned long long m = 0;
            #pragma unroll
            for (int k=0; k<16; k++){
                fx4 v = tp[k*64 + lane];      // cached (LLC-friendly) stream
                unsigned b = 0;
                b |= (v.x==0.f) ? 1u : 0u;
                b |= (v.y==0.f) ? 2u : 0u;
                b |= (v.z==0.f) ? 4u : 0u;
                b |= (v.w==0.f) ? 8u : 0u;
                m |= ((unsigned long long)b) << (k*4);
            }
            ushort* jp = jlds + g*ECAP;
            jp[lane] = 0; jp[64+lane] = 0; jp[128+lane] = 0;  // zero-pad tail
            int cnt = __popcll(m);
            int pre = cnt;
            #pragma unroll
            for (int off=1; off<64; off<<=1){
                int t = __shfl_up(pre, off);
                if (lane >= off) pre += t;
            }
            int ne = __shfl(pre, 63);
            if (ne > ECAP) ne = ECAP;
            int base = pre - cnt;
            unsigned long long mm = m;
            while (mm){
                int b = __builtin_ctzll(mm);
                mm &= mm - 1;
                if (base < ECAP)
                    jp[base] = (ushort)((b>>2)*256 + lane*4 + (b&3));
                base++;
            }
            if (lane == 0) nelds[g] = ne;
            __hip_atomic_store(&flagv[g], 1, __ATOMIC_RELEASE,
                               __HIP_MEMORY_SCOPE_WORKGROUP);
        }
        return;
    }

    // ================= CONSUMERS: C + D =================
    for (int g = wv; g < GPB; g += 3){
        int i = n0 + g;
        // spin (bounded for hang-safety; never trips in correct operation)
        int guard = 0;
        while (__hip_atomic_load(&flagv[g], __ATOMIC_ACQUIRE,
                                 __HIP_MEMORY_SCOPE_WORKGROUP) == 0){
            __builtin_amdgcn_s_sleep(2);
            if (++guard > (1<<24)) break;
        }
        int ne = nelds[g];
        const ushort* jp  = jlds + g*ECAP;
        ushort*       wpu = wbf  + wv*(ECAP*NHEAD);

        // ---- phase C: softmax stats (in-register butterflies) ------------
        float4 ss0 = *(const float4*)(s_src_t + (size_t)i*8);
        float4 ss1 = *(const float4*)(s_src_t + (size_t)i*8 + 4);
        float ssrc[8] = {ss0.x,ss0.y,ss0.z,ss0.w,ss1.x,ss1.y,ss1.z,ss1.w};

        float st[3][8];
        #pragma unroll
        for (int s=0; s<3; s++){
            int e = s*64 + lane;
            bool act = e < ne;
            int j = (int)jp[e];               // tail slots are 0 (safe)
            const float4* tpp = (const float4*)(s_tgt_t + (size_t)j*8);
            float4 a = tpp[0], b = tpp[1];
            st[s][0] = act ? a.x : -3.0e38f;
            st[s][1] = act ? a.y : -3.0e38f;
            st[s][2] = act ? a.z : -3.0e38f;
            st[s][3] = act ? a.w : -3.0e38f;
            st[s][4] = act ? b.x : -3.0e38f;
            st[s][5] = act ? b.y : -3.0e38f;
            st[s][6] = act ? b.z : -3.0e38f;
            st[s][7] = act ? b.w : -3.0e38f;
        }
        float M[8];
        #pragma unroll
        for (int hh=0; hh<8; hh++)
            M[hh] = fmaxf(fmaxf(st[0][hh], st[1][hh]), st[2][hh]);
        #pragma unroll
        for (int off=32; off; off>>=1)
            #pragma unroll
            for (int hh=0; hh<8; hh++)
                M[hh] = fmaxf(M[hh], __shfl_xor(M[hh], off));
        #pragma unroll
        for (int hh=0; hh<8; hh++)
            M[hh] = lrelu(ssrc[hh] + M[hh]);

        float den[8] = {0.f,0.f,0.f,0.f,0.f,0.f,0.f,0.f};
        #pragma unroll
        for (int s=0; s<3; s++){
            int e = s*64 + lane;
            bool act = e < ne;
            float wvv[8];
            #pragma unroll
            for (int hh=0; hh<8; hh++){
                float z = ssrc[hh] + st[s][hh];
                z = z > 0.f ? z : 0.2f*z;
                float ww = __expf(z - M[hh]);
                ww = act ? ww : 0.f;
                den[hh] += ww;
                wvv[hh] = ww;
            }
            uint p0 = (uint)f2b(wvv[0]) | ((uint)f2b(wvv[1])<<16);
            uint p1 = (uint)f2b(wvv[2]) | ((uint)f2b(wvv[3])<<16);
            uint p2 = (uint)f2b(wvv[4]) | ((uint)f2b(wvv[5])<<16);
            uint p3 = (uint)f2b(wvv[6]) | ((uint)f2b(wvv[7])<<16);
            *(uint4*)(wpu + e*8) = make_uint4(p0, p1, p2, p3);
        }
        #pragma unroll
        for (int off=32; off; off>>=1)
            #pragma unroll
            for (int hh=0; hh<8; hh++)
                den[hh] += __shfl_xor(den[hh], off);

        // ---- phase D: 8-edge batched gather-accumulate -------------------
        float acc[8] = {0.f,0.f,0.f,0.f,0.f,0.f,0.f,0.f};
        const char* pbb = (const char*)pb;
        uint laneoff = (uint)lane * 16;
        int ne8 = (ne + 7) & ~7;
        for (int e0=0; e0<ne8; e0+=8){
            uint4 jq = *(const uint4*)(jp + e0);          // 8 j's, one b128
            int jj[8] = { (int)(jq.x & 0xffffu), (int)(jq.x >> 16),
                          (int)(jq.y & 0xffffu), (int)(jq.y >> 16),
                          (int)(jq.z & 0xffffu), (int)(jq.z >> 16),
                          (int)(jq.w & 0xffffu), (int)(jq.w >> 16) };
            uint4 d[8];
            #pragma unroll
            for (int k=0; k<8; k++)                       // 8 loads in flight
                d[k] = *(const uint4*)(pbb + ((size_t)(uint)jj[k] << 10) + laneoff);
            #pragma unroll
            for (int k=0; k<8; k++){
                uint4 wd = *(const uint4*)(wpu + (e0+k)*8);   // bf16 w, b128
                acc[0] = fmaf(__uint_as_float(wd.x << 16), __uint_as_float(d[k].x << 16), acc[0]);
                acc[1] = fmaf(__uint_as_float(wd.x),       __uint_as_float(d[k].x),       acc[1]);
                acc[2] = fmaf(__uint_as_float(wd.y << 16), __uint_as_float(d[k].y << 16), acc[2]);
                acc[3] = fmaf(__uint_as_float(wd.y),       __uint_as_float(d[k].y),       acc[3]);
                acc[4] = fmaf(__uint_as_float(wd.z << 16), __uint_as_float(d[k].z << 16), acc[4]);
                acc[5] = fmaf(__uint_as_float(wd.z),       __uint_as_float(d[k].z),       acc[5]);
                acc[6] = fmaf(__uint_as_float(wd.w << 16), __uint_as_float(d[k].w << 16), acc[6]);
                acc[7] = fmaf(__uint_as_float(wd.w),       __uint_as_float(d[k].w),       acc[7]);
            }
        }

        // ---- head mean + skip + lrelu ------------------------------------
        float s = 0.f;
        #pragma unroll
        for (int hh=0; hh<8; hh++) s += acc[hh] / den[hh];
        float o = s*0.125f + skipbar[(size_t)i*64 + lane];
        out[(size_t)i*64 + lane] = lrelu(o);
    }
}

// ---------------------------------------------------------------------------
extern "C" void kernel_launch(void* const* d_in, const int* in_sizes, int n_in,
                              void* d_out, int out_size, void* d_ws, size_t ws_size,
                              hipStream_t stream){
    const float* x      = (const float*)d_in[0];
    const float* topo   = (const float*)d_in[1];
    const float* proj   = (const float*)d_in[2];
    const float* a_src  = (const float*)d_in[3];
    const float* a_tgt  = (const float*)d_in[4];
    const float* skip_w = (const float*)d_in[5];
    float* out = (float*)d_out;

    char* ws = (char*)d_ws;
    __hip_bfloat16* pb = (__hip_bfloat16*)ws;                 // 4 MB
    float*  skipbar = (float*)(ws + (4u<<20));                // 1 MB
    float*  s_src_t = (float*)(ws + (5u<<20));                // 128 KB
    float*  s_tgt_t = (float*)(ws + (5u<<20) + (128u<<10));   // 128 KB

    hipLaunchKernelGGL(k_gemm,  dim3(64, 9), dim3(256), 0, stream, x, proj, skip_w,
                       a_src, a_tgt, pb, s_src_t, s_tgt_t, skipbar);
    hipLaunchKernelGGL(k_fused, dim3(N_NODES/GPB), dim3(256), 0, stream, topo, pb,
                       s_src_t, s_tgt_t, skipbar, out);
}

// Round 12
// 52.038 us; speedup vs baseline: 1.1228x; 1.1228x over previous
//
#include <hip/hip_runtime.h>
#include <hip/hip_bf16.h>
#include <cstdint>

#define N_NODES 4096
#define FIN     128
#define FOUT    64
#define NHEAD   8
#define C_TOT   512   // NHEAD*FOUT
#define ECAP    192   // per-row edge capacity (= 3*64; mean deg ~82, sigma ~9)
#define LDK     136   // padded K-stride (bf16 elems)

typedef float fx4    __attribute__((ext_vector_type(4)));
typedef short bf16x8 __attribute__((ext_vector_type(8)));
typedef float f32x4  __attribute__((ext_vector_type(4)));

__device__ __forceinline__ float lrelu(float v){ return v > 0.f ? v : 0.2f*v; }

__device__ __forceinline__ ushort f2b(float f){
    uint u = __float_as_uint(f);
    return (ushort)((u + 0x7FFFu + ((u >> 16) & 1u)) >> 16);
}

// ---------------------------------------------------------------------------
// Kernel 1 "front": grid (64, 25).
//   blockIdx.y < 16 : MASK role. row = (x*16+y)*4 + wave. Streams topology
//     (nontemporal) and stores each lane's 64-bit edge mask to mword[row][lane]
//     (2 MB). Mask blocks dispatch FIRST (y-major order puts y=0..15 early for
//     each x), GEMM blocks backfill CUs -> MFMA hides under the HBM stream.
//   blockIdx.y >= 16: GEMM role (R6/R9/R10-proven body, coordinates intact):
//     n0 = x*64, h = y-16 (0..7 proj heads + svec epilogue, 8 = skip GEMM).
// ---------------------------------------------------------------------------
__global__ __launch_bounds__(256) void k_front(const float* __restrict__ x,
        const float* __restrict__ proj, const float* __restrict__ skip_w,
        const float* __restrict__ a_src, const float* __restrict__ a_tgt,
        const float* __restrict__ topo,
        __hip_bfloat16* __restrict__ pb, float* __restrict__ s_src_t,
        float* __restrict__ s_tgt_t, float* __restrict__ skipbar,
        unsigned long long* __restrict__ mword){
    __shared__ ushort xs[64*LDK];   // GEMM A tile
    __shared__ ushort bs[64*LDK];   // GEMM B^T tile
    int tid = threadIdx.x;

    if (blockIdx.y < 16){
        // ================= MASK role =================
        int lane = tid & 63, wv = tid >> 6;
        int row  = ((int)blockIdx.x*16 + (int)blockIdx.y)*4 + wv;
        const fx4* tp = (const fx4*)(topo + (size_t)row*N_NODES);
        unsigned long long m = 0;
        #pragma unroll
        for (int k=0; k<16; k++){
            fx4 v = __builtin_nontemporal_load(&tp[k*64 + lane]);
            unsigned b = 0;
            b |= (v.x==0.f) ? 1u : 0u;
            b |= (v.y==0.f) ? 2u : 0u;
            b |= (v.z==0.f) ? 4u : 0u;
            b |= (v.w==0.f) ? 8u : 0u;
            m |= ((unsigned long long)b) << (k*4);
        }
        mword[(size_t)row*64 + lane] = m;     // coalesced 512 B/wave
        return;
    }

    // ================= GEMM role (proven body) =================
    int n0 = blockIdx.x * 64;
    int h  = (int)blockIdx.y - 16;            // 0..7 head, 8 = skip

    #pragma unroll
    for (int k=0; k<8; k++){
        int q = tid + k*256;
        int r = q >> 5, f0 = (q & 31)*4;
        float4 v = *(const float4*)(x + (size_t)(n0+r)*FIN + f0);
        ushort4 u = make_ushort4(f2b(v.x), f2b(v.y), f2b(v.z), f2b(v.w));
        *(ushort4*)(xs + r*LDK + f0) = u;
    }
    if (h < 8){
        const float* B = proj + (size_t)h*FIN*FOUT;
        #pragma unroll
        for (int k=0; k<8; k++){
            int q = tid + k*256;
            int f = q >> 4, o0 = (q & 15)*4;
            float4 v = *(const float4*)(B + f*64 + o0);
            bs[(o0+0)*LDK + f] = f2b(v.x);
            bs[(o0+1)*LDK + f] = f2b(v.y);
            bs[(o0+2)*LDK + f] = f2b(v.z);
            bs[(o0+3)*LDK + f] = f2b(v.w);
        }
    } else {
        #pragma unroll
        for (int k=0; k<8; k++){
            int q = tid + k*256;
            int o = q >> 5, f0 = (q & 31)*4;
            float sx=0.f, sy=0.f, sz=0.f, sw=0.f;
            #pragma unroll
            for (int hh=0; hh<8; hh++){
                float4 v = *(const float4*)(skip_w + (size_t)(hh*64+o)*FIN + f0);
                sx += v.x; sy += v.y; sz += v.z; sw += v.w;
            }
            ushort4 u = make_ushort4(f2b(sx*0.125f), f2b(sy*0.125f),
                                     f2b(sz*0.125f), f2b(sw*0.125f));
            *(ushort4*)(bs + o*LDK + f0) = u;
        }
    }
    __syncthreads();

    int lane = tid & 63, w = tid >> 6;
    int r16 = lane & 15, kg = lane >> 4;
    f32x4 acc[4] = {{0.f,0.f,0.f,0.f},{0.f,0.f,0.f,0.f},
                    {0.f,0.f,0.f,0.f},{0.f,0.f,0.f,0.f}};
    const ushort* arow = xs + (w*16 + r16)*LDK + kg*8;
    #pragma unroll
    for (int ks=0; ks<4; ks++){
        bf16x8 a = *(const bf16x8*)(arow + ks*32);
        #pragma unroll
        for (int ct=0; ct<4; ct++){
            bf16x8 b = *(const bf16x8*)(bs + (ct*16 + r16)*LDK + ks*32 + kg*8);
            acc[ct] = __builtin_amdgcn_mfma_f32_16x16x32_bf16(a, b, acc[ct], 0, 0, 0);
        }
    }

    int rowbase = n0 + w*16 + kg*4;
    if (h < 8){
        float as[4], at[4];
        #pragma unroll
        for (int ct=0; ct<4; ct++){
            as[ct] = a_src[h*64 + ct*16 + r16];
            at[ct] = a_tgt[h*64 + ct*16 + r16];
        }
        ushort* pbu = (ushort*)pb;
        #pragma unroll
        for (int r=0; r<4; r++){
            float vs = 0.f, vt = 0.f;
            #pragma unroll
            for (int ct=0; ct<4; ct++){
                float v = acc[ct][r];
                vs = fmaf(v, as[ct], vs);
                vt = fmaf(v, at[ct], vt);
                pbu[(size_t)(rowbase+r)*C_TOT + (ct*16 + r16)*8 + h] = f2b(v);
            }
            #pragma unroll
            for (int off=1; off<16; off<<=1){
                vs += __shfl_xor(vs, off);
                vt += __shfl_xor(vt, off);
            }
            if (r16 == 0){
                s_src_t[(size_t)(rowbase+r)*8 + h] = vs;
                s_tgt_t[(size_t)(rowbase+r)*8 + h] = vt;
            }
        }
    } else {
        #pragma unroll
        for (int r=0; r<4; r++)
            #pragma unroll
            for (int ct=0; ct<4; ct++)
                skipbar[(size_t)(rowbase+r)*FOUT + ct*16 + r16] = acc[ct][r];
    }
}

// ---------------------------------------------------------------------------
// Kernel 2: fused compact + softmax + aggregation (R10-proven C/D phases).
//   One wave per node, zero __syncthreads. Phase A = one dwordx2 per lane.
// ---------------------------------------------------------------------------
__global__ __launch_bounds__(256) void k_fused(
        const unsigned long long* __restrict__ mword,
        const __hip_bfloat16* __restrict__ pb, const float* __restrict__ s_src_t,
        const float* __restrict__ s_tgt_t, const float* __restrict__ skipbar,
        float* __restrict__ out){
    __shared__ ushort jlds[4*ECAP];           // 1.5 KB  edge cols per wave
    __shared__ ushort wbf [4*ECAP*NHEAD];     // 12 KB   bf16 w strips per wave

    int lane = threadIdx.x & 63, wv = threadIdx.x >> 6;
    int i    = blockIdx.x*4 + wv;
    ushort* jp  = jlds + wv*ECAP;
    ushort* wpu = wbf  + wv*(ECAP*NHEAD);

    // ---- phase A': per-lane edge mask (bit k*4+c <-> col k*256+lane*4+c) --
    unsigned long long m = mword[(size_t)i*64 + lane];

    jp[lane] = 0; jp[64+lane] = 0; jp[128+lane] = 0;   // zero-pad tail

    // ---- phase B: lane prefix scan + compaction into LDS -----------------
    int cnt = __popcll(m);
    int pre = cnt;
    #pragma unroll
    for (int off=1; off<64; off<<=1){
        int t = __shfl_up(pre, off);
        if (lane >= off) pre += t;
    }
    int ne = __shfl(pre, 63);
    if (ne > ECAP) ne = ECAP;
    {
        int base = pre - cnt;
        unsigned long long mm = m;
        while (mm){
            int b = __builtin_ctzll(mm);
            mm &= mm - 1;
            if (base < ECAP)
                jp[base] = (ushort)((b>>2)*256 + lane*4 + (b&3));
            base++;
        }
    }
    // wave-synchronous LDS write->read within the same wave

    // ---- phase C: softmax stats (in-register butterflies) ----------------
    float4 ss0 = *(const float4*)(s_src_t + (size_t)i*8);
    float4 ss1 = *(const float4*)(s_src_t + (size_t)i*8 + 4);
    float ssrc[8] = {ss0.x,ss0.y,ss0.z,ss0.w,ss1.x,ss1.y,ss1.z,ss1.w};

    float st[3][8];
    #pragma unroll
    for (int s=0; s<3; s++){
        int e = s*64 + lane;
        bool act = e < ne;
        int j = act ? (int)jp[e] : 0;
        const float4* tpp = (const float4*)(s_tgt_t + (size_t)j*8);
        float4 a = tpp[0], b = tpp[1];
        st[s][0] = act ? a.x : -3.0e38f;
        st[s][1] = act ? a.y : -3.0e38f;
        st[s][2] = act ? a.z : -3.0e38f;
        st[s][3] = act ? a.w : -3.0e38f;
        st[s][4] = act ? b.x : -3.0e38f;
        st[s][5] = act ? b.y : -3.0e38f;
        st[s][6] = act ? b.z : -3.0e38f;
        st[s][7] = act ? b.w : -3.0e38f;
    }
    float M[8];
    #pragma unroll
    for (int hh=0; hh<8; hh++)
        M[hh] = fmaxf(fmaxf(st[0][hh], st[1][hh]), st[2][hh]);
    #pragma unroll
    for (int off=32; off; off>>=1)
        #pragma unroll
        for (int hh=0; hh<8; hh++)
            M[hh] = fmaxf(M[hh], __shfl_xor(M[hh], off));
    #pragma unroll
    for (int hh=0; hh<8; hh++)
        M[hh] = lrelu(ssrc[hh] + M[hh]);

    float den[8] = {0.f,0.f,0.f,0.f,0.f,0.f,0.f,0.f};
    #pragma unroll
    for (int s=0; s<3; s++){
        int e = s*64 + lane;
        bool act = e < ne;
        float wvv[8];
        #pragma unroll
        for (int hh=0; hh<8; hh++){
            float z = ssrc[hh] + st[s][hh];
            z = z > 0.f ? z : 0.2f*z;
            float ww = __expf(z - M[hh]);
            ww = act ? ww : 0.f;
            den[hh] += ww;
            wvv[hh] = ww;
        }
        uint p0 = (uint)f2b(wvv[0]) | ((uint)f2b(wvv[1])<<16);
        uint p1 = (uint)f2b(wvv[2]) | ((uint)f2b(wvv[3])<<16);
        uint p2 = (uint)f2b(wvv[4]) | ((uint)f2b(wvv[5])<<16);
        uint p3 = (uint)f2b(wvv[6]) | ((uint)f2b(wvv[7])<<16);
        *(uint4*)(wpu + e*8) = make_uint4(p0, p1, p2, p3);
    }
    #pragma unroll
    for (int off=32; off; off>>=1)
        #pragma unroll
        for (int hh=0; hh<8; hh++)
            den[hh] += __shfl_xor(den[hh], off);

    // ---- phase D: 8-edge batched gather-accumulate -----------------------
    float acc[8] = {0.f,0.f,0.f,0.f,0.f,0.f,0.f,0.f};
    const char* pbb = (const char*)pb;
    uint laneoff = (uint)lane * 16;
    int ne8 = (ne + 7) & ~7;
    for (int e0=0; e0<ne8; e0+=8){
        uint4 jq = *(const uint4*)(jp + e0);              // 8 j's, one b128
        int jj[8] = { (int)(jq.x & 0xffffu), (int)(jq.x >> 16),
                      (int)(jq.y & 0xffffu), (int)(jq.y >> 16),
                      (int)(jq.z & 0xffffu), (int)(jq.z >> 16),
                      (int)(jq.w & 0xffffu), (int)(jq.w >> 16) };
        uint4 d[8];
        #pragma unroll
        for (int k=0; k<8; k++)                           // 8 loads in flight
            d[k] = *(const uint4*)(pbb + ((size_t)(uint)jj[k] << 10) + laneoff);
        #pragma unroll
        for (int k=0; k<8; k++){
            uint4 wd = *(const uint4*)(wpu + (e0+k)*8);   // bf16 w, one b128
            acc[0] = fmaf(__uint_as_float(wd.x << 16), __uint_as_float(d[k].x << 16), acc[0]);
            acc[1] = fmaf(__uint_as_float(wd.x),       __uint_as_float(d[k].x),       acc[1]);
            acc[2] = fmaf(__uint_as_float(wd.y << 16), __uint_as_float(d[k].y << 16), acc[2]);
            acc[3] = fmaf(__uint_as_float(wd.y),       __uint_as_float(d[k].y),       acc[3]);
            acc[4] = fmaf(__uint_as_float(wd.z << 16), __uint_as_float(d[k].z << 16), acc[4]);
            acc[5] = fmaf(__uint_as_float(wd.z),       __uint_as_float(d[k].z),       acc[5]);
            acc[6] = fmaf(__uint_as_float(wd.w << 16), __uint_as_float(d[k].w << 16), acc[6]);
            acc[7] = fmaf(__uint_as_float(wd.w),       __uint_as_float(d[k].w),       acc[7]);
        }
    }

    // ---- head mean + skip + lrelu ----------------------------------------
    float s = 0.f;
    #pragma unroll
    for (int hh=0; hh<8; hh++) s += acc[hh] / den[hh];
    float o = s*0.125f + skipbar[(size_t)i*64 + lane];
    out[(size_t)i*64 + lane] = lrelu(o);
}

// ---------------------------------------------------------------------------
extern "C" void kernel_launch(void* const* d_in, const int* in_sizes, int n_in,
                              void* d_out, int out_size, void* d_ws, size_t ws_size,
                              hipStream_t stream){
    const float* x      = (const float*)d_in[0];
    const float* topo   = (const float*)d_in[1];
    const float* proj   = (const float*)d_in[2];
    const float* a_src  = (const float*)d_in[3];
    const float* a_tgt  = (const float*)d_in[4];
    const float* skip_w = (const float*)d_in[5];
    float* out = (float*)d_out;

    char* ws = (char*)d_ws;
    __hip_bfloat16* pb = (__hip_bfloat16*)ws;                 // 4 MB
    float*  skipbar = (float*)(ws + (4u<<20));                // 1 MB
    float*  s_src_t = (float*)(ws + (5u<<20));                // 128 KB
    float*  s_tgt_t = (float*)(ws + (5u<<20) + (128u<<10));   // 128 KB
    unsigned long long* mword =
        (unsigned long long*)(ws + (5u<<20) + (256u<<10));    // 2 MB

    hipLaunchKernelGGL(k_front, dim3(64, 25), dim3(256), 0, stream,
                       x, proj, skip_w, a_src, a_tgt, topo,
                       pb, s_src_t, s_tgt_t, skipbar, mword);
    hipLaunchKernelGGL(k_fused, dim3(1024), dim3(256), 0, stream,
                       mword, pb, s_src_t, s_tgt_t, skipbar, out);
}

// Round 14
// 51.189 us; speedup vs baseline: 1.1414x; 1.0166x over previous
//
#include <hip/hip_runtime.h>
#include <hip/hip_bf16.h>
#include <cstdint>

#define N_NODES 4096
#define FIN     128
#define FOUT    64
#define NHEAD   8
#define C_TOT   512   // NHEAD*FOUT
#define HECAP   128   // per-half-row edge capacity; MUST be 2*64 so the
                      // unconditional 2-slot C2 store exactly tiles the strip
#define LDK     136   // padded K-stride (bf16 elems)

typedef float fx4    __attribute__((ext_vector_type(4)));
typedef short bf16x8 __attribute__((ext_vector_type(8)));
typedef float f32x4  __attribute__((ext_vector_type(4)));

__device__ __forceinline__ float lrelu(float v){ return v > 0.f ? v : 0.2f*v; }

__device__ __forceinline__ ushort f2b(float f){
    uint u = __float_as_uint(f);
    return (ushort)((u + 0x7FFFu + ((u >> 16) & 1u)) >> 16);
}

// ---------------------------------------------------------------------------
// Kernel 1: MFMA bf16 GEMM (R6-proven, unchanged). grid (64, 9), 256 thr.
// ---------------------------------------------------------------------------
__global__ __launch_bounds__(256) void k_gemm(const float* __restrict__ x,
        const float* __restrict__ proj, const float* __restrict__ skip_w,
        const float* __restrict__ a_src, const float* __restrict__ a_tgt,
        __hip_bfloat16* __restrict__ pb, float* __restrict__ s_src_t,
        float* __restrict__ s_tgt_t, float* __restrict__ skipbar){
    __shared__ ushort xs[64*LDK];
    __shared__ ushort bs[64*LDK];
    int tid = threadIdx.x;
    int n0  = blockIdx.x * 64;
    int h   = blockIdx.y;

    #pragma unroll
    for (int k=0; k<8; k++){
        int q = tid + k*256;
        int r = q >> 5, f0 = (q & 31)*4;
        float4 v = *(const float4*)(x + (size_t)(n0+r)*FIN + f0);
        ushort4 u = make_ushort4(f2b(v.x), f2b(v.y), f2b(v.z), f2b(v.w));
        *(ushort4*)(xs + r*LDK + f0) = u;
    }
    if (h < 8){
        const float* B = proj + (size_t)h*FIN*FOUT;
        #pragma unroll
        for (int k=0; k<8; k++){
            int q = tid + k*256;
            int f = q >> 4, o0 = (q & 15)*4;
            float4 v = *(const float4*)(B + f*64 + o0);
            bs[(o0+0)*LDK + f] = f2b(v.x);
            bs[(o0+1)*LDK + f] = f2b(v.y);
            bs[(o0+2)*LDK + f] = f2b(v.z);
            bs[(o0+3)*LDK + f] = f2b(v.w);
        }
    } else {
        #pragma unroll
        for (int k=0; k<8; k++){
            int q = tid + k*256;
            int o = q >> 5, f0 = (q & 31)*4;
            float sx=0.f, sy=0.f, sz=0.f, sw=0.f;
            #pragma unroll
            for (int hh=0; hh<8; hh++){
                float4 v = *(const float4*)(skip_w + (size_t)(hh*64+o)*FIN + f0);
                sx += v.x; sy += v.y; sz += v.z; sw += v.w;
            }
            ushort4 u = make_ushort4(f2b(sx*0.125f), f2b(sy*0.125f),
                                     f2b(sz*0.125f), f2b(sw*0.125f));
            *(ushort4*)(bs + o*LDK + f0) = u;
        }
    }
    __syncthreads();

    int lane = tid & 63, w = tid >> 6;
    int r16 = lane & 15, kg = lane >> 4;
    f32x4 acc[4] = {{0.f,0.f,0.f,0.f},{0.f,0.f,0.f,0.f},
                    {0.f,0.f,0.f,0.f},{0.f,0.f,0.f,0.f}};
    const ushort* arow = xs + (w*16 + r16)*LDK + kg*8;
    #pragma unroll
    for (int ks=0; ks<4; ks++){
        bf16x8 a = *(const bf16x8*)(arow + ks*32);
        #pragma unroll
        for (int ct=0; ct<4; ct++){
            bf16x8 b = *(const bf16x8*)(bs + (ct*16 + r16)*LDK + ks*32 + kg*8);
            acc[ct] = __builtin_amdgcn_mfma_f32_16x16x32_bf16(a, b, acc[ct], 0, 0, 0);
        }
    }

    int rowbase = n0 + w*16 + kg*4;
    if (h < 8){
        float as[4], at[4];
        #pragma unroll
        for (int ct=0; ct<4; ct++){
            as[ct] = a_src[h*64 + ct*16 + r16];
            at[ct] = a_tgt[h*64 + ct*16 + r16];
        }
        ushort* pbu = (ushort*)pb;
        #pragma unroll
        for (int r=0; r<4; r++){
            float vs = 0.f, vt = 0.f;
            #pragma unroll
            for (int ct=0; ct<4; ct++){
                float v = acc[ct][r];
                vs = fmaf(v, as[ct], vs);
                vt = fmaf(v, at[ct], vt);
                pbu[(size_t)(rowbase+r)*C_TOT + (ct*16 + r16)*8 + h] = f2b(v);
            }
            #pragma unroll
            for (int off=1; off<16; off<<=1){
                vs += __shfl_xor(vs, off);
                vt += __shfl_xor(vt, off);
            }
            if (r16 == 0){
                s_src_t[(size_t)(rowbase+r)*8 + h] = vs;
                s_tgt_t[(size_t)(rowbase+r)*8 + h] = vt;
            }
        }
    } else {
        #pragma unroll
        for (int r=0; r<4; r++)
            #pragma unroll
            for (int ct=0; ct<4; ct++)
                skipbar[(size_t)(rowbase+r)*FOUT + ct*16 + r16] = acc[ct][r];
    }
}

// ---------------------------------------------------------------------------
// Kernel 2: fused GAT, TWO WAVES PER NODE (half-row split).
//   Block = 256 thr = 4 waves = 2 nodes; wave wv: node g=wv>>1, half hf=wv&1.
//   Each wave: stream its 8 KB half-row -> 32-bit masks -> compact own edges
//   (~41) -> softmax stats for own edges -> gather-accumulate own edges.
//   Cross-wave exchange: max partials (barrier 1), den+acc partials (barrier 2).
// ---------------------------------------------------------------------------
__global__ __launch_bounds__(256) void k_fused(const float* __restrict__ topo,
        const __hip_bfloat16* __restrict__ pb, const float* __restrict__ s_src_t,
        const float* __restrict__ s_tgt_t, const float* __restrict__ skipbar,
        float* __restrict__ out){
    __shared__ ushort jlds[4*HECAP];          // 1 KB   per-wave edge cols
    __shared__ ushort wbf [4*HECAP*NHEAD];    // 8 KB   per-wave bf16 w strips
    __shared__ float  Mpart[4][8];
    __shared__ float  denp [4][8];
    __shared__ float  accx [2][8][64];        // 4 KB   odd-wave acc dump

    int tid  = threadIdx.x;
    int lane = tid & 63, wv = tid >> 6;
    int g = wv >> 1, hf = wv & 1;
    int i = blockIdx.x*2 + g;
    ushort* jp  = jlds + wv*HECAP;
    ushort* wpu = wbf  + wv*(HECAP*NHEAD);

    jp[lane] = 0; jp[64 + lane] = 0;          // zero-pad full 128-entry strip

    // ---- phase A: stream OWN half-row (8 KB), build 32-bit edge mask -----
    const fx4* tp = (const fx4*)(topo + (size_t)i*N_NODES + hf*2048);
    uint m = 0;
    #pragma unroll
    for (int k=0; k<8; k++){
        fx4 v = __builtin_nontemporal_load(&tp[k*64 + lane]);
        uint b = 0;
        b |= (v.x==0.f) ? 1u : 0u;
        b |= (v.y==0.f) ? 2u : 0u;
        b |= (v.z==0.f) ? 4u : 0u;
        b |= (v.w==0.f) ? 8u : 0u;
        m |= b << (k*4);
    }

    // ---- phase B: lane prefix scan + compaction into own strip -----------
    int cnt = __popc(m);
    int pre = cnt;
    #pragma unroll
    for (int off=1; off<64; off<<=1){
        int t = __shfl_up(pre, off);
        if (lane >= off) pre += t;
    }
    int neh = __shfl(pre, 63);
    if (neh > HECAP) neh = HECAP;
    {
        int base = pre - cnt;
        uint mm = m;
        int cbase = lane*4 + hf*2048;
        while (mm){
            int b = __builtin_ctz(mm);
            mm &= mm - 1;
            if (base < HECAP)
                jp[base] = (ushort)((b>>2)*256 + cbase + (b&3));
            base++;
        }
    }
    // wave-synchronous LDS write->read within the same wave

    // ---- phase C1: per-head raw max over own edges -----------------------
    float4 ss0 = *(const float4*)(s_src_t + (size_t)i*8);
    float4 ss1 = *(const float4*)(s_src_t + (size_t)i*8 + 4);
    float ssrc[8] = {ss0.x,ss0.y,ss0.z,ss0.w,ss1.x,ss1.y,ss1.z,ss1.w};

    float st[2][8];
    #pragma unroll
    for (int s=0; s<2; s++){
        int e = s*64 + lane;
        bool act = e < neh;
        int j = act ? (int)jp[e] : 0;
        const float4* tpp = (const float4*)(s_tgt_t + (size_t)j*8);
        float4 a = tpp[0], b = tpp[1];
        st[s][0] = act ? a.x : -3.0e38f;
        st[s][1] = act ? a.y : -3.0e38f;
        st[s][2] = act ? a.z : -3.0e38f;
        st[s][3] = act ? a.w : -3.0e38f;
        st[s][4] = act ? b.x : -3.0e38f;
        st[s][5] = act ? b.y : -3.0e38f;
        st[s][6] = act ? b.z : -3.0e38f;
        st[s][7] = act ? b.w : -3.0e38f;
    }
    float Mx[8];
    #pragma unroll
    for (int hh=0; hh<8; hh++) Mx[hh] = fmaxf(st[0][hh], st[1][hh]);
    #pragma unroll
    for (int off=32; off; off>>=1)
        #pragma unroll
        for (int hh=0; hh<8; hh++)
            Mx[hh] = fmaxf(Mx[hh], __shfl_xor(Mx[hh], off));
    if (lane == 0){
        #pragma unroll
        for (int hh=0; hh<8; hh++) Mpart[wv][hh] = Mx[hh];
    }
    __syncthreads();                          // barrier 1: max exchange

    float M[8];
    #pragma unroll
    for (int hh=0; hh<8; hh++)
        M[hh] = lrelu(ssrc[hh] + fmaxf(Mpart[wv][hh], Mpart[wv^1][hh]));

    // ---- phase C2: w = exp(lrelu(ssrc+st) - M); partial den; w -> strip --
    float den[8] = {0.f,0.f,0.f,0.f,0.f,0.f,0.f,0.f};
    #pragma unroll
    for (int s=0; s<2; s++){
        int e = s*64 + lane;
        bool act = e < neh;
        float wvv[8];
        #pragma unroll
        for (int hh=0; hh<8; hh++){
            float z = ssrc[hh] + st[s][hh];
            z = z > 0.f ? z : 0.2f*z;
            float ww = __expf(z - M[hh]);
            ww = act ? ww : 0.f;
            den[hh] += ww;
            wvv[hh] = ww;
        }
        uint p0 = (uint)f2b(wvv[0]) | ((uint)f2b(wvv[1])<<16);
        uint p1 = (uint)f2b(wvv[2]) | ((uint)f2b(wvv[3])<<16);
        uint p2 = (uint)f2b(wvv[4]) | ((uint)f2b(wvv[5])<<16);
        uint p3 = (uint)f2b(wvv[6]) | ((uint)f2b(wvv[7])<<16);
        *(uint4*)(wpu + e*8) = make_uint4(p0, p1, p2, p3);   // e<128=HECAP: in-strip
    }
    #pragma unroll
    for (int off=32; off; off>>=1)
        #pragma unroll
        for (int hh=0; hh<8; hh++)
            den[hh] += __shfl_xor(den[hh], off);
    if (lane == 0){
        #pragma unroll
        for (int hh=0; hh<8; hh++) denp[wv][hh] = den[hh];
    }

    // ---- phase D: 8-edge batched gather-accumulate over OWN edges --------
    float acc[8] = {0.f,0.f,0.f,0.f,0.f,0.f,0.f,0.f};
    const char* pbb = (const char*)pb;
    uint laneoff = (uint)lane * 16;
    int ne8 = (neh + 7) & ~7;
    for (int e0=0; e0<ne8; e0+=8){
        uint4 jq = *(const uint4*)(jp + e0);              // 8 j's, one b128
        int jj[8] = { (int)(jq.x & 0xffffu), (int)(jq.x >> 16),
                      (int)(jq.y & 0xffffu), (int)(jq.y >> 16),
                      (int)(jq.z & 0xffffu), (int)(jq.z >> 16),
                      (int)(jq.w & 0xffffu), (int)(jq.w >> 16) };
        uint4 d[8];
        #pragma unroll
        for (int k=0; k<8; k++)                           // 8 loads in flight
            d[k] = *(const uint4*)(pbb + ((size_t)(uint)jj[k] << 10) + laneoff);
        #pragma unroll
        for (int k=0; k<8; k++){
            uint4 wd = *(const uint4*)(wpu + (e0+k)*8);   // bf16 w, one b128
            acc[0] = fmaf(__uint_as_float(wd.x << 16), __uint_as_float(d[k].x << 16), acc[0]);
            acc[1] = fmaf(__uint_as_float(wd.x),       __uint_as_float(d[k].x),       acc[1]);
            acc[2] = fmaf(__uint_as_float(wd.y << 16), __uint_as_float(d[k].y << 16), acc[2]);
            acc[3] = fmaf(__uint_as_float(wd.y),       __uint_as_float(d[k].y),       acc[3]);
            acc[4] = fmaf(__uint_as_float(wd.z << 16), __uint_as_float(d[k].z << 16), acc[4]);
            acc[5] = fmaf(__uint_as_float(wd.z),       __uint_as_float(d[k].z),       acc[5]);
            acc[6] = fmaf(__uint_as_float(wd.w << 16), __uint_as_float(d[k].w << 16), acc[6]);
            acc[7] = fmaf(__uint_as_float(wd.w),       __uint_as_float(d[k].w),       acc[7]);
        }
    }

    // ---- combine halves + epilogue ---------------------------------------
    if (hf == 1){
        #pragma unroll
        for (int hh=0; hh<8; hh++) accx[g][hh][lane] = acc[hh];
    }
    __syncthreads();                          // barrier 2: den+acc exchange
    if (hf == 0){
        float s = 0.f;
        #pragma unroll
        for (int hh=0; hh<8; hh++){
            float a  = acc[hh] + accx[g][hh][lane];
            float dn = denp[wv][hh] + denp[wv+1][hh];
            s += a / dn;
        }
        float o = s*0.125f + skipbar[(size_t)i*64 + lane];
        out[(size_t)i*64 + lane] = lrelu(o);
    }
}

// ---------------------------------------------------------------------------
extern "C" void kernel_launch(void* const* d_in, const int* in_sizes, int n_in,
                              void* d_out, int out_size, void* d_ws, size_t ws_size,
                              hipStream_t stream){
    const float* x      = (const float*)d_in[0];
    const float* topo   = (const float*)d_in[1];
    const float* proj   = (const float*)d_in[2];
    const float* a_src  = (const float*)d_in[3];
    const float* a_tgt  = (const float*)d_in[4];
    const float* skip_w = (const float*)d_in[5];
    float* out = (float*)d_out;

    char* ws = (char*)d_ws;
    __hip_bfloat16* pb = (__hip_bfloat16*)ws;                 // 4 MB
    float*  skipbar = (float*)(ws + (4u<<20));                // 1 MB
    float*  s_src_t = (float*)(ws + (5u<<20));                // 128 KB
    float*  s_tgt_t = (float*)(ws + (5u<<20) + (128u<<10));   // 128 KB

    hipLaunchKernelGGL(k_gemm,  dim3(64, 9), dim3(256), 0, stream, x, proj, skip_w,
                       a_src, a_tgt, pb, s_src_t, s_tgt_t, skipbar);
    hipLaunchKernelGGL(k_fused, dim3(N_NODES/2), dim3(256), 0, stream, topo, pb,
                       s_src_t, s_tgt_t, skipbar, out);
}

// Round 16
// 45.118 us; speedup vs baseline: 1.2950x; 1.1346x over previous
//
#include <hip/hip_runtime.h>
#include <hip/hip_bf16.h>
#include <cstdint>

#define N_NODES 4096
#define FIN     128
#define FOUT    64
#define NHEAD   8
#define C_TOT   512   // NHEAD*FOUT
#define ECAP    192   // per-row edge capacity (= 3*64 exactly; mean ~82, sigma ~9)
#define LDK     136   // padded K-stride (f16 elems)

typedef float    fx4  __attribute__((ext_vector_type(4)));
typedef short  bf16x8 __attribute__((ext_vector_type(8)));
typedef float  f32x4  __attribute__((ext_vector_type(4)));
typedef _Float16 h2   __attribute__((ext_vector_type(2)));

__device__ __forceinline__ float lrelu(float v){ return v > 0.f ? v : 0.2f*v; }

__device__ __forceinline__ ushort f2b(float f){      // f32 -> bf16 bits (RNE)
    uint u = __float_as_uint(f);
    return (ushort)((u + 0x7FFFu + ((u >> 16) & 1u)) >> 16);
}
__device__ __forceinline__ ushort f2h(float f){      // f32 -> f16 bits (RNE)
    _Float16 h = (_Float16)f;
    return __builtin_bit_cast(ushort, h);
}
__device__ __forceinline__ h2 as_h2(uint u){ return __builtin_bit_cast(h2, u); }
__device__ __forceinline__ uint pkh(float a, float b){
    return (uint)f2h(a) | ((uint)f2h(b) << 16);
}

#if __has_builtin(__builtin_amdgcn_fdot2)
#define FDOT2(a,b,c) __builtin_amdgcn_fdot2((a),(b),(c),false)
#else
__device__ __forceinline__ float FDOT2(h2 a, h2 b, float c){
    return c + (float)a[0]*(float)b[0] + (float)a[1]*(float)b[1];
}
#endif

// ---------------------------------------------------------------------------
// Kernel 1: MFMA bf16 GEMM (R6-proven structure). grid (64, 9), 256 thr.
//   y = 0..7 : p-head GEMM + svec epilogue + **f16** head-minor store pb
//   y = 8    : skip GEMM with inline head-averaged skip_w (f32 out)
// ---------------------------------------------------------------------------
__global__ __launch_bounds__(256) void k_gemm(const float* __restrict__ x,
        const float* __restrict__ proj, const float* __restrict__ skip_w,
        const float* __restrict__ a_src, const float* __restrict__ a_tgt,
        ushort* __restrict__ pb, float* __restrict__ s_src_t,
        float* __restrict__ s_tgt_t, float* __restrict__ skipbar){
    __shared__ ushort xs[64*LDK];
    __shared__ ushort bs[64*LDK];
    int tid = threadIdx.x;
    int n0  = blockIdx.x * 64;
    int h   = blockIdx.y;

    #pragma unroll
    for (int k=0; k<8; k++){
        int q = tid + k*256;
        int r = q >> 5, f0 = (q & 31)*4;
        float4 v = *(const float4*)(x + (size_t)(n0+r)*FIN + f0);
        ushort4 u = make_ushort4(f2b(v.x), f2b(v.y), f2b(v.z), f2b(v.w));
        *(ushort4*)(xs + r*LDK + f0) = u;
    }
    if (h < 8){
        const float* B = proj + (size_t)h*FIN*FOUT;
        #pragma unroll
        for (int k=0; k<8; k++){
            int q = tid + k*256;
            int f = q >> 4, o0 = (q & 15)*4;
            float4 v = *(const float4*)(B + f*64 + o0);
            bs[(o0+0)*LDK + f] = f2b(v.x);
            bs[(o0+1)*LDK + f] = f2b(v.y);
            bs[(o0+2)*LDK + f] = f2b(v.z);
            bs[(o0+3)*LDK + f] = f2b(v.w);
        }
    } else {
        #pragma unroll
        for (int k=0; k<8; k++){
            int q = tid + k*256;
            int o = q >> 5, f0 = (q & 31)*4;
            float sx=0.f, sy=0.f, sz=0.f, sw=0.f;
            #pragma unroll
            for (int hh=0; hh<8; hh++){
                float4 v = *(const float4*)(skip_w + (size_t)(hh*64+o)*FIN + f0);
                sx += v.x; sy += v.y; sz += v.z; sw += v.w;
            }
            ushort4 u = make_ushort4(f2b(sx*0.125f), f2b(sy*0.125f),
                                     f2b(sz*0.125f), f2b(sw*0.125f));
            *(ushort4*)(bs + o*LDK + f0) = u;
        }
    }
    __syncthreads();

    int lane = tid & 63, w = tid >> 6;
    int r16 = lane & 15, kg = lane >> 4;
    f32x4 acc[4] = {{0.f,0.f,0.f,0.f},{0.f,0.f,0.f,0.f},
                    {0.f,0.f,0.f,0.f},{0.f,0.f,0.f,0.f}};
    const ushort* arow = xs + (w*16 + r16)*LDK + kg*8;
    #pragma unroll
    for (int ks=0; ks<4; ks++){
        bf16x8 a = *(const bf16x8*)(arow + ks*32);
        #pragma unroll
        for (int ct=0; ct<4; ct++){
            bf16x8 b = *(const bf16x8*)(bs + (ct*16 + r16)*LDK + ks*32 + kg*8);
            acc[ct] = __builtin_amdgcn_mfma_f32_16x16x32_bf16(a, b, acc[ct], 0, 0, 0);
        }
    }

    int rowbase = n0 + w*16 + kg*4;
    if (h < 8){
        float as[4], at[4];
        #pragma unroll
        for (int ct=0; ct<4; ct++){
            as[ct] = a_src[h*64 + ct*16 + r16];
            at[ct] = a_tgt[h*64 + ct*16 + r16];
        }
        #pragma unroll
        for (int r=0; r<4; r++){
            float vs = 0.f, vt = 0.f;
            #pragma unroll
            for (int ct=0; ct<4; ct++){
                float v = acc[ct][r];
                vs = fmaf(v, as[ct], vs);
                vt = fmaf(v, at[ct], vt);
                pb[(size_t)(rowbase+r)*C_TOT + (ct*16 + r16)*8 + h] = f2h(v);
            }
            #pragma unroll
            for (int off=1; off<16; off<<=1){
                vs += __shfl_xor(vs, off);
                vt += __shfl_xor(vt, off);
            }
            if (r16 == 0){
                s_src_t[(size_t)(rowbase+r)*8 + h] = vs;
                s_tgt_t[(size_t)(rowbase+r)*8 + h] = vt;
            }
        }
    } else {
        #pragma unroll
        for (int r=0; r<4; r++)
            #pragma unroll
            for (int ct=0; ct<4; ct++)
                skipbar[(size_t)(rowbase+r)*FOUT + ct*16 + r16] = acc[ct][r];
    }
}

// ---------------------------------------------------------------------------
// Kernel 2: fused GAT (R9 skeleton), dot-product phase D.
//   One wave per node, zero __syncthreads.
//   w' = w/den pre-scaled, f16-packed; edge list stored as BYTE OFFSETS
//   (j<<10); per edge: 1 LDS b128 (w') + 1 gather + 4 v_dot2_f32_f16.
// ---------------------------------------------------------------------------
__global__ __launch_bounds__(256) void k_fused(const float* __restrict__ topo,
        const ushort* __restrict__ pb, const float* __restrict__ s_src_t,
        const float* __restrict__ s_tgt_t, const float* __restrict__ skipbar,
        float* __restrict__ out){
    __shared__ uint   jpo [4*ECAP];           // 3 KB  per-wave edge byte-offsets
    __shared__ ushort wbf [4*ECAP*NHEAD];     // 12 KB per-wave f16 w' strips

    int lane = threadIdx.x & 63, wv = threadIdx.x >> 6;
    int i    = blockIdx.x*4 + wv;
    uint*   jp  = jpo + wv*ECAP;
    ushort* wpu = wbf + wv*(ECAP*NHEAD);

    jp[lane] = 0; jp[64+lane] = 0; jp[128+lane] = 0;   // zero-pad tail

    // ---- phase A: stream topology row, build 64-bit edge mask ------------
    const fx4* tp = (const fx4*)(topo + (size_t)i*N_NODES);
    unsigned long long m = 0;
    #pragma unroll
    for (int k=0; k<16; k++){
        fx4 v = __builtin_nontemporal_load(&tp[k*64 + lane]);
        unsigned b = 0;
        b |= (v.x==0.f) ? 1u : 0u;
        b |= (v.y==0.f) ? 2u : 0u;
        b |= (v.z==0.f) ? 4u : 0u;
        b |= (v.w==0.f) ? 8u : 0u;
        m |= ((unsigned long long)b) << (k*4);
    }

    // ---- phase B: lane prefix scan + compaction (byte offsets) -----------
    int cnt = __popcll(m);
    int pre = cnt;
    #pragma unroll
    for (int off=1; off<64; off<<=1){
        int t = __shfl_up(pre, off);
        if (lane >= off) pre += t;
    }
    int ne = __shfl(pre, 63);
    if (ne > ECAP) ne = ECAP;
    {
        int base = pre - cnt;
        unsigned long long mm = m;
        while (mm){
            int b = __builtin_ctzll(mm);
            mm &= mm - 1;
            if (base < ECAP)
                jp[base] = (uint)((b>>2)*256 + lane*4 + (b&3)) << 10;
            base++;
        }
    }
    // wave-synchronous LDS write->read within the same wave

    // ---- phase C: softmax stats; w kept in registers ---------------------
    float4 ss0 = *(const float4*)(s_src_t + (size_t)i*8);
    float4 ss1 = *(const float4*)(s_src_t + (size_t)i*8 + 4);
    float ssrc[8] = {ss0.x,ss0.y,ss0.z,ss0.w,ss1.x,ss1.y,ss1.z,ss1.w};

    float st[3][8];
    #pragma unroll
    for (int s=0; s<3; s++){
        int e = s*64 + lane;
        bool act = e < ne;
        int j = act ? (int)(jp[e] >> 10) : 0;
        const float4* tpp = (const float4*)(s_tgt_t + (size_t)j*8);
        float4 a = tpp[0], b = tpp[1];
        st[s][0] = act ? a.x : -3.0e38f;
        st[s][1] = act ? a.y : -3.0e38f;
        st[s][2] = act ? a.z : -3.0e38f;
        st[s][3] = act ? a.w : -3.0e38f;
        st[s][4] = act ? b.x : -3.0e38f;
        st[s][5] = act ? b.y : -3.0e38f;
        st[s][6] = act ? b.z : -3.0e38f;
        st[s][7] = act ? b.w : -3.0e38f;
    }
    float M[8];
    #pragma unroll
    for (int hh=0; hh<8; hh++)
        M[hh] = fmaxf(fmaxf(st[0][hh], st[1][hh]), st[2][hh]);
    #pragma unroll
    for (int off=32; off; off>>=1)
        #pragma unroll
        for (int hh=0; hh<8; hh++)
            M[hh] = fmaxf(M[hh], __shfl_xor(M[hh], off));
    #pragma unroll
    for (int hh=0; hh<8; hh++)
        M[hh] = lrelu(ssrc[hh] + M[hh]);

    float den[8] = {0.f,0.f,0.f,0.f,0.f,0.f,0.f,0.f};
    float wreg[3][8];
    #pragma unroll
    for (int s=0; s<3; s++){
        int e = s*64 + lane;
        bool act = e < ne;
        #pragma unroll
        for (int hh=0; hh<8; hh++){
            float z = ssrc[hh] + st[s][hh];
            z = z > 0.f ? z : 0.2f*z;
            float ww = __expf(z - M[hh]);
            ww = act ? ww : 0.f;
            den[hh] += ww;
            wreg[s][hh] = ww;
        }
    }
    #pragma unroll
    for (int off=32; off; off>>=1)
        #pragma unroll
        for (int hh=0; hh<8; hh++)
            den[hh] += __shfl_xor(den[hh], off);
    float rden[8];
    #pragma unroll
    for (int hh=0; hh<8; hh++) rden[hh] = 1.f / den[hh];

    // pack w' = w * (1/den) as f16 pairs -> strips (unconditional: 3*64=ECAP)
    #pragma unroll
    for (int s=0; s<3; s++){
        int e = s*64 + lane;
        *(uint4*)(wpu + e*8) = make_uint4(
            pkh(wreg[s][0]*rden[0], wreg[s][1]*rden[1]),
            pkh(wreg[s][2]*rden[2], wreg[s][3]*rden[3]),
            pkh(wreg[s][4]*rden[4], wreg[s][5]*rden[5]),
            pkh(wreg[s][6]*rden[6], wreg[s][7]*rden[7]));
    }

    // ---- phase D: 8-edge batches; 4 dot2 per edge, single f32 accumulator -
    float acc = 0.f;
    const char* pbb = (const char*)pb;
    uint laneoff = (uint)lane * 16;
    int ne8 = (ne + 7) & ~7;
    for (int e0=0; e0<ne8; e0+=8){
        uint4 ja = *(const uint4*)(jp + e0);              // 4 byte-offsets
        uint4 jb = *(const uint4*)(jp + e0 + 4);          // 4 more
        uint off[8] = {ja.x, ja.y, ja.z, ja.w, jb.x, jb.y, jb.z, jb.w};
        uint4 d[8];
        #pragma unroll
        for (int k=0; k<8; k++)                           // 8 loads in flight
            d[k] = *(const uint4*)(pbb + off[k] + laneoff);
        #pragma unroll
        for (int k=0; k<8; k++){
            uint4 wq = *(const uint4*)(wpu + (e0+k)*8);   // f16 w', one b128
            acc = FDOT2(as_h2(wq.x), as_h2(d[k].x), acc);
            acc = FDOT2(as_h2(wq.y), as_h2(d[k].y), acc);
            acc = FDOT2(as_h2(wq.z), as_h2(d[k].z), acc);
            acc = FDOT2(as_h2(wq.w), as_h2(d[k].w), acc);
        }
    }

    // ---- epilogue: head mean + skip + lrelu ------------------------------
    float o = acc*0.125f + skipbar[(size_t)i*64 + lane];
    out[(size_t)i*64 + lane] = lrelu(o);
}

// ---------------------------------------------------------------------------
extern "C" void kernel_launch(void* const* d_in, const int* in_sizes, int n_in,
                              void* d_out, int out_size, void* d_ws, size_t ws_size,
                              hipStream_t stream){
    const float* x      = (const float*)d_in[0];
    const float* topo   = (const float*)d_in[1];
    const float* proj   = (const float*)d_in[2];
    const float* a_src  = (const float*)d_in[3];
    const float* a_tgt  = (const float*)d_in[4];
    const float* skip_w = (const float*)d_in[5];
    float* out = (float*)d_out;

    char* ws = (char*)d_ws;
    ushort* pb      = (ushort*)ws;                            // 4 MB (f16)
    float*  skipbar = (float*)(ws + (4u<<20));                // 1 MB
    float*  s_src_t = (float*)(ws + (5u<<20));                // 128 KB
    float*  s_tgt_t = (float*)(ws + (5u<<20) + (128u<<10));   // 128 KB

    hipLaunchKernelGGL(k_gemm,  dim3(64, 9), dim3(256), 0, stream, x, proj, skip_w,
                       a_src, a_tgt, pb, s_src_t, s_tgt_t, skipbar);
    hipLaunchKernelGGL(k_fused, dim3(1024),  dim3(256), 0, stream, topo, pb,
                       s_src_t, s_tgt_t, skipbar, out);
}